// Round 1
// baseline (65520.129 us; speedup 1.0000x reference)
//
#include <hip/hip_runtime.h>

// 2-layer LSTM, B=64, T=1024, D_IN=256, H=512, fp32.
// Single persistent cooperative kernel:
//  - 256 blocks x 512 threads (1 block/CU). Blocks [0,128): layer0, [128,256): layer1.
//  - Layers pipelined: at superstep s, layer0 does t=s, layer1 does t=s-1.
//    => exactly one grid barrier per superstep (1024 total).
//  - Each block owns 4 h-indices (x4 gate types = 16 gate rows) for ALL 64 batches.
//    c-state lives in registers (thread t<256: b=t&63, hh=t>>6), h-state ping-pongs in ws.
//  - Per step: K-sliced (Ks=128) LDS staging of W-slice + combined [h | x or h0] slice,
//    register-accumulated dot products, LDS regroup for the cell.
//  - Custom two-level (16x16) grid barrier with agent-scope acq/rel atomics + threadfence.

#define BB   64
#define TT   1024
#define DIN  256
#define HH   512
#define K0   768     // [h0_prev(512) | x_t(256)]
#define K1   1024    // [h1_prev(512) | h0_t(512)]
#define KS   128
#define NTHR 512
#define ROWS 16      // 4 h-indices x 4 gate types
#define RS   (KS + 4)

__global__ __launch_bounds__(NTHR) void lstm_fused(
    const float* __restrict__ x,
    const float* __restrict__ W0, const float* __restrict__ b0v,
    const float* __restrict__ W1, const float* __restrict__ b1v,
    float* __restrict__ out, float* __restrict__ hws, unsigned* __restrict__ bar)
{
    __shared__ float Wl[ROWS][RS];      // 16 x 132 fp32  (~8.4 KB)
    __shared__ float Cb[BB][RS];        // 64 x 132 fp32  (~33.8 KB)
    __shared__ float Gb[BB][ROWS + 1];  // gates regroup  (~4.4 KB)
    __shared__ float biasl[ROWS];

    const int tid   = threadIdx.x;
    const int bid   = blockIdx.x;
    const int layer = bid >> 7;      // 0 or 1
    const int j     = bid & 127;
    const int hbase = j << 2;        // 4 h-indices per block

    const float* Wm = layer ? W1 : W0;
    const float* bv = layer ? b1v : b0v;
    const int K     = layer ? K1 : K0;
    const int nsl   = K / KS;        // 8 or 6

    float* h0b = hws;                   // [2][64][512]
    float* h1b = hws + 2 * BB * HH;     // [2][64][512]

    if (tid < ROWS)
        biasl[tid] = bv[(tid >> 2) * HH + hbase + (tid & 3)];
    __syncthreads();

    const int g  = tid & 15;         // gate row within block (ty = g>>2, hh = g&3)
    const int bq = tid >> 4;         // 0..31 ; handles batches bq and bq+32
    float creg = 0.0f;               // persistent cell state (valid for tid<256)
    unsigned epoch = 0;
    const size_t YOFF = (size_t)BB * TT * HH;

    for (int s = 0; s <= TT; ++s) {
        const bool active = layer ? (s >= 1) : (s < TT);
        if (active) {
            const int t = layer ? (s - 1) : s;
            const float* hprev = (layer ? h1b : h0b) + (s & 1) * BB * HH;
            const float* h0cur = h0b + (s & 1) * BB * HH;

            float4 A0 = {0.f, 0.f, 0.f, 0.f};
            float4 A1 = {0.f, 0.f, 0.f, 0.f};

            for (int sl = 0; sl < nsl; ++sl) {
                const int bk = sl * KS;
                // ---- stage W slice: 16 rows x 128 floats (one float4/thread) ----
                {
                    const int r = tid >> 5, c4 = tid & 31;
                    const int grow = (r >> 2) * HH + hbase + (r & 3);
                    const float4 wv = *(const float4*)(Wm + (size_t)grow * K + bk + (c4 << 2));
                    *(float4*)&Wl[r][c4 << 2] = wv;
                }
                // ---- stage comb slice: 64 rows x 128 floats (4 float4/thread) ----
#pragma unroll
                for (int m = 0; m < 4; ++m) {
                    const int fi = tid + NTHR * m;   // 0..2047
                    const int br = fi >> 5, c4 = fi & 31;
                    const int kk = bk + (c4 << 2);
                    float4 v;
                    if (bk < HH) {
                        v = *(const float4*)(hprev + br * HH + kk);
                    } else if (layer == 0) {
                        v = *(const float4*)(x + ((size_t)br * TT + t) * DIN + (kk - HH));
                    } else {
                        v = *(const float4*)(h0cur + br * HH + (kk - HH));
                    }
                    *(float4*)&Cb[br][c4 << 2] = v;
                }
                __syncthreads();
                // ---- dot: this thread computes gates (bq,g) and (bq+32,g) ----
#pragma unroll 8
                for (int k4 = 0; k4 < KS / 4; ++k4) {
                    const float4 w  = *(const float4*)&Wl[g][k4 << 2];
                    const float4 ca = *(const float4*)&Cb[bq][k4 << 2];
                    const float4 cb = *(const float4*)&Cb[bq + 32][k4 << 2];
                    A0.x += w.x * ca.x; A0.y += w.y * ca.y;
                    A0.z += w.z * ca.z; A0.w += w.w * ca.w;
                    A1.x += w.x * cb.x; A1.y += w.y * cb.y;
                    A1.z += w.z * cb.z; A1.w += w.w * cb.w;
                }
                __syncthreads();
            }
            const float bias = biasl[g];
            Gb[bq][g]      = bias + ((A0.x + A0.y) + (A0.z + A0.w));
            Gb[bq + 32][g] = bias + ((A1.x + A1.y) + (A1.z + A1.w));
            __syncthreads();
            // ---- cell: 256 threads, one (b, hh) each; c stays in creg ----
            if (tid < 256) {
                const int b   = tid & 63;
                const int hh2 = tid >> 6;
                const float ig = Gb[b][hh2];
                const float fg = Gb[b][4 + hh2];
                const float gg = Gb[b][8 + hh2];
                const float og = Gb[b][12 + hh2];
                const float si = 1.0f / (1.0f + __expf(-ig));
                const float sf = 1.0f / (1.0f + __expf(-fg));
                const float so = 1.0f / (1.0f + __expf(-og));
                const float c  = sf * creg + si * tanhf(gg);
                creg = c;
                const float h  = so * tanhf(c);
                const int hidx = hbase + hh2;
                const int wpar = (s + 1) & 1;
                if (layer == 0) {
                    h0b[wpar * BB * HH + b * HH + hidx] = h;
                    if (t == TT - 1) {
                        out[YOFF + (size_t)b * HH + hidx] = h;                 // h_n[0]
                        out[YOFF + 2 * BB * HH + (size_t)b * HH + hidx] = c;   // c_n[0]
                    }
                } else {
                    out[((size_t)b * TT + t) * HH + hidx] = h;                 // y[b,t,:]
                    h1b[wpar * BB * HH + b * HH + hidx] = h;
                    if (t == TT - 1) {
                        out[YOFF + BB * HH + (size_t)b * HH + hidx] = h;       // h_n[1]
                        out[YOFF + 3 * BB * HH + (size_t)b * HH + hidx] = c;   // c_n[1]
                    }
                }
            }
        }
        // ---- grid barrier (two-level 16x16), every superstep except the last ----
        if (s < TT) {
            __syncthreads();
            if (tid == 0) {
                __threadfence();  // release: make h/out writes device-visible
                const unsigned target = ++epoch;
                unsigned* leafp = bar + 64 + ((unsigned)bid >> 4) * 32;
                const unsigned r = __hip_atomic_fetch_add(leafp, 1u, __ATOMIC_ACQ_REL,
                                                          __HIP_MEMORY_SCOPE_AGENT);
                if (r == 15u) {
                    __hip_atomic_store(leafp, 0u, __ATOMIC_RELAXED, __HIP_MEMORY_SCOPE_AGENT);
                    const unsigned rr = __hip_atomic_fetch_add(bar + 32, 1u, __ATOMIC_ACQ_REL,
                                                               __HIP_MEMORY_SCOPE_AGENT);
                    if (rr == 15u) {
                        __hip_atomic_store(bar + 32, 0u, __ATOMIC_RELAXED,
                                           __HIP_MEMORY_SCOPE_AGENT);
                        __hip_atomic_fetch_add(bar, 1u, __ATOMIC_RELEASE,
                                               __HIP_MEMORY_SCOPE_AGENT);
                    }
                }
                while (__hip_atomic_load(bar, __ATOMIC_ACQUIRE,
                                         __HIP_MEMORY_SCOPE_AGENT) < target) {
                    __builtin_amdgcn_s_sleep(4);
                }
                __threadfence();  // acquire: invalidate stale cached h
            }
            __syncthreads();
        }
    }
}

extern "C" void kernel_launch(void* const* d_in, const int* in_sizes, int n_in,
                              void* d_out, int out_size, void* d_ws, size_t ws_size,
                              hipStream_t stream) {
    (void)in_sizes; (void)n_in; (void)out_size; (void)ws_size;
    const float* x  = (const float*)d_in[0];
    const float* W0 = (const float*)d_in[1];
    const float* b0 = (const float*)d_in[2];
    const float* W1 = (const float*)d_in[3];
    const float* b1 = (const float*)d_in[4];
    float* out = (float*)d_out;
    float* hws = (float*)d_ws;                       // 2x2x64x512 fp32 = 512 KB h state
    unsigned* bar = (unsigned*)((char*)d_ws + 2 * 2 * 64 * 512 * sizeof(float));

    // zero h-state ping-pong buffers + barrier state (ws is poisoned 0xAA each call)
    hipMemsetAsync(d_ws, 0, 2 * 2 * 64 * 512 * sizeof(float) + 4096, stream);

    void* args[] = { (void*)&x, (void*)&W0, (void*)&b0, (void*)&W1, (void*)&b1,
                     (void*)&out, (void*)&hws, (void*)&bar };
    hipLaunchCooperativeKernel(reinterpret_cast<const void*>(lstm_fused),
                               dim3(256), dim3(512), args, 0u, stream);
}

// Round 2
// 46739.532 us; speedup vs baseline: 1.4018x; 1.4018x over previous
//
#include <hip/hip_runtime.h>

// 2-layer LSTM, B=64, T=1024, D_IN=256, H=512, fp32 in/out.
// R2: MFMA (16x16x32 bf16) with split-bf16 (hi+lo) operands for ~fp32 accuracy.
//  - 256 blocks x 512 threads (1 block/CU). Blocks [0,128): layer0, [128,256): layer1.
//  - Pipelined layers, one grid barrier per superstep (as R1, proven correct).
//  - Each block: 16 gate rows (4 h-idx x 4 gate types) x all 64 batches.
//  - W fragments: split hi/lo bf16, PERSISTENT IN REGISTERS across all steps
//    (per wave: k-slice of 128 = 4 k-steps x (hi+lo) short8 = 32 VGPRs).
//  - h exchanged as pre-split hi/lo bf16 SoA buffers in ws; B-fragments loaded
//    directly from global (no LDS staging, no per-step conversion VALU).
//  - 8-way cross-wave K-reduction via LDS (padded), then cell (c in registers).

#define BB   64
#define TT   1024
#define DIN  256
#define HH   512
#define K0   768     // [h0_prev(512) | x_t(256)]
#define K1   1024    // [h1_prev(512) | h0_t(512)]
#define NTHR 512

typedef float f32x4 __attribute__((ext_vector_type(4)));
typedef short short8 __attribute__((ext_vector_type(8)));

__device__ __forceinline__ void splitf(float f, short& h, short& l) {
    const unsigned u = __float_as_uint(f);
    const float fh = __uint_as_float(u & 0xffff0000u);
    h = (short)(u >> 16);
    l = (short)(__float_as_uint(f - fh) >> 16);
}

__device__ __forceinline__ void split8(f32x4 a, f32x4 b, short8& hi, short8& lo) {
#pragma unroll
    for (int j = 0; j < 4; ++j) {
        short h0, l0, h1, l1;
        splitf(a[j], h0, l0);
        splitf(b[j], h1, l1);
        hi[j] = h0; lo[j] = l0;
        hi[j + 4] = h1; lo[j + 4] = l1;
    }
}

__global__ __launch_bounds__(NTHR) void lstm_fused(
    const float* __restrict__ x,
    const float* __restrict__ W0, const float* __restrict__ b0v,
    const float* __restrict__ W1, const float* __restrict__ b1v,
    float* __restrict__ out, short* __restrict__ hws, unsigned* __restrict__ bar)
{
    __shared__ float Red[8][16][68];    // per-wave K-partials, padded (34.8 KB)
    __shared__ float Gb[BB][17];        // gates regroup (4.4 KB)
    __shared__ float biasl[16];

    const int tid   = threadIdx.x;
    const int bid   = blockIdx.x;
    const int layer = bid >> 7;
    const int hbase = (bid & 127) << 2;

    const float* Wm = layer ? W1 : W0;
    const float* bv = layer ? b1v : b0v;
    const int K     = layer ? K1 : K0;

    // hi/lo bf16 SoA h-state buffers, each [2 parities][64][512] shorts
    short* H0HI = hws;
    short* H0LO = hws + 2 * BB * HH;
    short* H1HI = hws + 4 * BB * HH;
    short* H1LO = hws + 6 * BB * HH;

    if (tid < 16)
        biasl[tid] = bv[(tid >> 2) * HH + hbase + (tid & 3)];

    const int w     = tid >> 6;        // wave 0..7 (K-slice owner)
    const int lane  = tid & 63;
    const int quad  = lane >> 4;       // 0..3
    const int lm    = lane & 15;       // fragment row (m or n)
    const int kbase = w << 7;          // wave's K offset (128 each)
    const int grow  = (lm >> 2) * HH + hbase + (lm & 3);   // global W row for m=lm

    // ---- persistent W fragments: hi/lo bf16, 4 k-steps of 32 ----
    short8 whi[4], wlo[4];
#pragma unroll
    for (int ks = 0; ks < 4; ++ks) {
        short8 hi = {0, 0, 0, 0, 0, 0, 0, 0};
        short8 lo = {0, 0, 0, 0, 0, 0, 0, 0};
        const int kb = kbase + ks * 32;
        if (kb < K) {
            const int k0 = kb + quad * 8;
            const float* p = Wm + (size_t)grow * K + k0;
            split8(*(const f32x4*)p, *(const f32x4*)(p + 4), hi, lo);
        }
        whi[ks] = hi; wlo[ks] = lo;
    }
    __syncthreads();

    float creg = 0.0f;                 // persistent cell state (tid<256: b=tid&63, hh=tid>>6)
    unsigned epoch = 0;
    const size_t YOFF = (size_t)BB * TT * HH;

    for (int s = 0; s <= TT; ++s) {
        const bool active = layer ? (s >= 1) : (s < TT);
        if (active) {
            const int t   = layer ? (s - 1) : s;
            const int par = (s & 1) * BB * HH;
            const short* hpHi = (layer ? H1HI : H0HI) + par;
            const short* hpLo = (layer ? H1LO : H0LO) + par;
            const short* hcHi = H0HI + par;            // layer1: h0 of current t
            const short* hcLo = H0LO + par;

            f32x4 acc[4];
#pragma unroll
            for (int nt = 0; nt < 4; ++nt) acc[nt] = (f32x4){0.f, 0.f, 0.f, 0.f};

#pragma unroll
            for (int ks = 0; ks < 4; ++ks) {
                const int kb = kbase + ks * 32;
                if (kb < K) {
                    const int k0 = kb + quad * 8;
#pragma unroll
                    for (int nt = 0; nt < 4; ++nt) {
                        const int n = (nt << 4) + lm;
                        short8 chi, clo;
                        if (kb < HH) {
                            chi = *(const short8*)(hpHi + n * HH + k0);
                            clo = *(const short8*)(hpLo + n * HH + k0);
                        } else if (layer) {
                            chi = *(const short8*)(hcHi + n * HH + (k0 - HH));
                            clo = *(const short8*)(hcLo + n * HH + (k0 - HH));
                        } else {
                            const float* p = x + ((size_t)n * TT + t) * DIN + (k0 - HH);
                            split8(*(const f32x4*)p, *(const f32x4*)(p + 4), chi, clo);
                        }
                        acc[nt] = __builtin_amdgcn_mfma_f32_16x16x32_bf16(whi[ks], chi, acc[nt], 0, 0, 0);
                        acc[nt] = __builtin_amdgcn_mfma_f32_16x16x32_bf16(whi[ks], clo, acc[nt], 0, 0, 0);
                        acc[nt] = __builtin_amdgcn_mfma_f32_16x16x32_bf16(wlo[ks], chi, acc[nt], 0, 0, 0);
                    }
                }
            }
            // ---- dump K-partials: D[m=quad*4+r][n=nt*16+lm] ----
#pragma unroll
            for (int nt = 0; nt < 4; ++nt)
#pragma unroll
                for (int r = 0; r < 4; ++r)
                    Red[w][quad * 4 + r][(nt << 4) + lm] = acc[nt][r];
            __syncthreads();
            // ---- 8-way reduce + bias: thread -> (row=tid&15, batches tid>>4, +32) ----
            {
                const int row = tid & 15, b0 = tid >> 4;
                float s0 = biasl[row], s1 = biasl[row];
#pragma unroll
                for (int ww = 0; ww < 8; ++ww) {
                    s0 += Red[ww][row][b0];
                    s1 += Red[ww][row][b0 + 32];
                }
                Gb[b0][row] = s0;
                Gb[b0 + 32][row] = s1;
            }
            __syncthreads();
            // ---- cell: 256 threads, one (b, hh) each; c stays in creg ----
            if (tid < 256) {
                const int b   = tid & 63;
                const int hh2 = tid >> 6;
                const float ig = Gb[b][hh2];
                const float fg = Gb[b][4 + hh2];
                const float gg = Gb[b][8 + hh2];
                const float og = Gb[b][12 + hh2];
                const float si = 1.0f / (1.0f + __expf(-ig));
                const float sf = 1.0f / (1.0f + __expf(-fg));
                const float so = 1.0f / (1.0f + __expf(-og));
                const float c  = sf * creg + si * tanhf(gg);
                creg = c;
                const float h  = so * tanhf(c);
                const int hidx = hbase + hh2;
                const int wpar = ((s + 1) & 1) * BB * HH;
                short hhi, hlo;
                splitf(h, hhi, hlo);
                if (layer == 0) {
                    H0HI[wpar + b * HH + hidx] = hhi;
                    H0LO[wpar + b * HH + hidx] = hlo;
                    if (t == TT - 1) {
                        out[YOFF + (size_t)b * HH + hidx] = h;                 // h_n[0]
                        out[YOFF + 2 * BB * HH + (size_t)b * HH + hidx] = c;   // c_n[0]
                    }
                } else {
                    out[((size_t)b * TT + t) * HH + hidx] = h;                 // y[b,t,:]
                    H1HI[wpar + b * HH + hidx] = hhi;
                    H1LO[wpar + b * HH + hidx] = hlo;
                    if (t == TT - 1) {
                        out[YOFF + BB * HH + (size_t)b * HH + hidx] = h;       // h_n[1]
                        out[YOFF + 3 * BB * HH + (size_t)b * HH + hidx] = c;   // c_n[1]
                    }
                }
            }
        }
        // ---- grid barrier (two-level 16x16), proven in R1 ----
        if (s < TT) {
            __syncthreads();
            if (tid == 0) {
                __threadfence();
                const unsigned target = ++epoch;
                unsigned* leafp = bar + 64 + ((unsigned)bid >> 4) * 32;
                const unsigned r = __hip_atomic_fetch_add(leafp, 1u, __ATOMIC_ACQ_REL,
                                                          __HIP_MEMORY_SCOPE_AGENT);
                if (r == 15u) {
                    __hip_atomic_store(leafp, 0u, __ATOMIC_RELAXED, __HIP_MEMORY_SCOPE_AGENT);
                    const unsigned rr = __hip_atomic_fetch_add(bar + 32, 1u, __ATOMIC_ACQ_REL,
                                                               __HIP_MEMORY_SCOPE_AGENT);
                    if (rr == 15u) {
                        __hip_atomic_store(bar + 32, 0u, __ATOMIC_RELAXED,
                                           __HIP_MEMORY_SCOPE_AGENT);
                        __hip_atomic_fetch_add(bar, 1u, __ATOMIC_RELEASE,
                                               __HIP_MEMORY_SCOPE_AGENT);
                    }
                }
                while (__hip_atomic_load(bar, __ATOMIC_ACQUIRE,
                                         __HIP_MEMORY_SCOPE_AGENT) < target) {
                    __builtin_amdgcn_s_sleep(4);
                }
                __threadfence();
            }
            __syncthreads();
        }
    }
}

extern "C" void kernel_launch(void* const* d_in, const int* in_sizes, int n_in,
                              void* d_out, int out_size, void* d_ws, size_t ws_size,
                              hipStream_t stream) {
    (void)in_sizes; (void)n_in; (void)out_size; (void)ws_size;
    const float* x  = (const float*)d_in[0];
    const float* W0 = (const float*)d_in[1];
    const float* b0 = (const float*)d_in[2];
    const float* W1 = (const float*)d_in[3];
    const float* b1 = (const float*)d_in[4];
    float* out = (float*)d_out;
    short* hws = (short*)d_ws;   // 4 buffers x [2][64][512] shorts = 512 KB
    unsigned* bar = (unsigned*)((char*)d_ws + 4 * 2 * 64 * 512 * sizeof(short));

    hipMemsetAsync(d_ws, 0, 4 * 2 * 64 * 512 * sizeof(short) + 4096, stream);

    void* args[] = { (void*)&x, (void*)&W0, (void*)&b0, (void*)&W1, (void*)&b1,
                     (void*)&out, (void*)&hws, (void*)&bar };
    hipLaunchCooperativeKernel(reinterpret_cast<const void*>(lstm_fused),
                               dim3(256), dim3(512), args, 0u, stream);
}

// Round 3
// 20940.112 us; speedup vs baseline: 3.1289x; 2.2321x over previous
//
#include <hip/hip_runtime.h>

// 2-layer LSTM, B=64, T=1024, D_IN=256, H=512, fp32 in/out.
// R3: same MFMA split-bf16 compute as R2; synchronization rebuilt to avoid
// L2-wide cache maintenance (no __threadfence, no ACQ_REL fences):
//  - h state: one u32 per element (bf16 hi | bf16 lo), written via RELAXED
//    AGENT atomic stores (sc0sc1 write-through; never dirty in L2).
//  - h reads: RELAXED AGENT atomic u64 loads (sc1: bypass stale L1/L2, read L3),
//    unpacked with v_perm_b32. x read with plain cached loads (read-only).
//  - grid barrier: monotonic two-level counters, all RELAXED AGENT atomics.
//    __syncthreads() before arrival drains every thread's vmcnt (write-through
//    stores then globally visible); no resets -> no cross-address ordering hazard.

#define BB   64
#define TT   1024
#define DIN  256
#define HH   512
#define K0   768     // [h0_prev(512) | x_t(256)]
#define K1   1024    // [h1_prev(512) | h0_t(512)]
#define NTHR 512

typedef float f32x4 __attribute__((ext_vector_type(4)));
typedef short short8 __attribute__((ext_vector_type(8)));

union S8U4 { short8 s; unsigned u[4]; };

__device__ __forceinline__ void splitf(float f, short& h, short& l) {
    const unsigned u = __float_as_uint(f);
    const float fh = __uint_as_float(u & 0xffff0000u);
    h = (short)(u >> 16);
    l = (short)(__float_as_uint(f - fh) >> 16);
}

__device__ __forceinline__ void split8(f32x4 a, f32x4 b, short8& hi, short8& lo) {
#pragma unroll
    for (int j = 0; j < 4; ++j) {
        short h0, l0, h1, l1;
        splitf(a[j], h0, l0);
        splitf(b[j], h1, l1);
        hi[j] = h0; lo[j] = l0;
        hi[j + 4] = h1; lo[j + 4] = l1;
    }
}

__device__ __forceinline__ unsigned packhl(float f) {
    const unsigned u = __float_as_uint(f);
    const float fh = __uint_as_float(u & 0xffff0000u);
    const unsigned l = __float_as_uint(f - fh) >> 16;
    return (u >> 16) | (l << 16);     // bytes 0-1: hi bf16, bytes 2-3: lo bf16
}

// Load one MFMA B fragment-pair (8 k-elements) from packed h buffer, device-coherent.
__device__ __forceinline__ void load_hfrag(const unsigned* base, int n, int k0,
                                           short8& chi, short8& clo) {
    const unsigned long long* p = (const unsigned long long*)(base + n * HH + k0);
    S8U4 hi, lo;
#pragma unroll
    for (int j = 0; j < 4; ++j) {
        const unsigned long long d =
            __hip_atomic_load(p + j, __ATOMIC_RELAXED, __HIP_MEMORY_SCOPE_AGENT);
        const unsigned u0 = (unsigned)d, u1 = (unsigned)(d >> 32);
        hi.u[j] = __builtin_amdgcn_perm(u1, u0, 0x05040100u);  // hi16 of both elems
        lo.u[j] = __builtin_amdgcn_perm(u1, u0, 0x07060302u);  // lo16 of both elems
    }
    chi = hi.s; clo = lo.s;
}

__global__ __launch_bounds__(NTHR) void lstm_fused(
    const float* __restrict__ x,
    const float* __restrict__ W0, const float* __restrict__ b0v,
    const float* __restrict__ W1, const float* __restrict__ b1v,
    float* __restrict__ out, unsigned* __restrict__ hws, unsigned* __restrict__ bar)
{
    __shared__ float Red[8][16][68];    // per-wave K-partials, padded (34.8 KB)
    __shared__ float Gb[BB][17];        // gates regroup (4.4 KB)
    __shared__ float biasl[16];

    const int tid   = threadIdx.x;
    const int bid   = blockIdx.x;
    const int layer = bid >> 7;
    const int hbase = (bid & 127) << 2;

    const float* Wm = layer ? W1 : W0;
    const float* bv = layer ? b1v : b0v;
    const int K     = layer ? K1 : K0;

    // packed (hi|lo) h buffers: each [2 parities][64][512] u32
    unsigned* HP0 = hws;
    unsigned* HP1 = hws + 2 * BB * HH;

    if (tid < 16)
        biasl[tid] = bv[(tid >> 2) * HH + hbase + (tid & 3)];

    const int w     = tid >> 6;        // wave 0..7 (K-slice owner)
    const int lane  = tid & 63;
    const int quad  = lane >> 4;       // 0..3
    const int lm    = lane & 15;       // fragment row (m or n)
    const int kbase = w << 7;          // wave's K offset (128 each)
    const int grow  = (lm >> 2) * HH + hbase + (lm & 3);

    // ---- persistent W fragments: hi/lo bf16, 4 k-steps of 32 ----
    short8 whi[4], wlo[4];
#pragma unroll
    for (int ks = 0; ks < 4; ++ks) {
        short8 hi = {0, 0, 0, 0, 0, 0, 0, 0};
        short8 lo = {0, 0, 0, 0, 0, 0, 0, 0};
        const int kb = kbase + ks * 32;
        if (kb < K) {
            const int k0 = kb + quad * 8;
            const float* p = Wm + (size_t)grow * K + k0;
            split8(*(const f32x4*)p, *(const f32x4*)(p + 4), hi, lo);
        }
        whi[ks] = hi; wlo[ks] = lo;
    }
    __syncthreads();

    float creg = 0.0f;                 // persistent cell state (tid<256)
    unsigned epoch = 0;
    const size_t YOFF = (size_t)BB * TT * HH;

    for (int s = 0; s <= TT; ++s) {
        const bool active = layer ? (s >= 1) : (s < TT);
        if (active) {
            const int t   = layer ? (s - 1) : s;
            const int par = (s & 1) * BB * HH;
            const unsigned* hp = (layer ? HP1 : HP0) + par;
            const unsigned* hc = HP0 + par;   // layer1: h0 of current t

            f32x4 acc[4];
#pragma unroll
            for (int nt = 0; nt < 4; ++nt) acc[nt] = (f32x4){0.f, 0.f, 0.f, 0.f};

#pragma unroll
            for (int ks = 0; ks < 4; ++ks) {
                const int kb = kbase + ks * 32;
                if (kb < K) {
                    const int k0 = kb + quad * 8;
#pragma unroll
                    for (int nt = 0; nt < 4; ++nt) {
                        const int n = (nt << 4) + lm;
                        short8 chi, clo;
                        if (kb < HH) {
                            load_hfrag(hp, n, k0, chi, clo);
                        } else if (layer) {
                            load_hfrag(hc, n, k0 - HH, chi, clo);
                        } else {
                            const float* p = x + ((size_t)n * TT + t) * DIN + (k0 - HH);
                            split8(*(const f32x4*)p, *(const f32x4*)(p + 4), chi, clo);
                        }
                        acc[nt] = __builtin_amdgcn_mfma_f32_16x16x32_bf16(whi[ks], chi, acc[nt], 0, 0, 0);
                        acc[nt] = __builtin_amdgcn_mfma_f32_16x16x32_bf16(whi[ks], clo, acc[nt], 0, 0, 0);
                        acc[nt] = __builtin_amdgcn_mfma_f32_16x16x32_bf16(wlo[ks], chi, acc[nt], 0, 0, 0);
                    }
                }
            }
            // ---- dump K-partials: D[m=quad*4+r][n=nt*16+lm] ----
#pragma unroll
            for (int nt = 0; nt < 4; ++nt)
#pragma unroll
                for (int r = 0; r < 4; ++r)
                    Red[w][quad * 4 + r][(nt << 4) + lm] = acc[nt][r];
            __syncthreads();
            // ---- 8-way reduce + bias ----
            {
                const int row = tid & 15, b0 = tid >> 4;
                float s0 = biasl[row], s1 = biasl[row];
#pragma unroll
                for (int ww = 0; ww < 8; ++ww) {
                    s0 += Red[ww][row][b0];
                    s1 += Red[ww][row][b0 + 32];
                }
                Gb[b0][row] = s0;
                Gb[b0 + 32][row] = s1;
            }
            __syncthreads();
            // ---- cell: 256 threads, one (b, hh) each; c stays in creg ----
            if (tid < 256) {
                const int b   = tid & 63;
                const int hh2 = tid >> 6;
                const float ig = Gb[b][hh2];
                const float fg = Gb[b][4 + hh2];
                const float gg = Gb[b][8 + hh2];
                const float og = Gb[b][12 + hh2];
                const float si = 1.0f / (1.0f + __expf(-ig));
                const float sf = 1.0f / (1.0f + __expf(-fg));
                const float so = 1.0f / (1.0f + __expf(-og));
                const float c  = sf * creg + si * tanhf(gg);
                creg = c;
                const float h  = so * tanhf(c);
                const int hidx = hbase + hh2;
                const int wpar = ((s + 1) & 1) * BB * HH;
                const unsigned packed = packhl(h);
                if (layer == 0) {
                    __hip_atomic_store(&HP0[wpar + b * HH + hidx], packed,
                                       __ATOMIC_RELAXED, __HIP_MEMORY_SCOPE_AGENT);
                    if (t == TT - 1) {
                        out[YOFF + (size_t)b * HH + hidx] = h;                 // h_n[0]
                        out[YOFF + 2 * BB * HH + (size_t)b * HH + hidx] = c;   // c_n[0]
                    }
                } else {
                    out[((size_t)b * TT + t) * HH + hidx] = h;                 // y[b,t,:]
                    __hip_atomic_store(&HP1[wpar + b * HH + hidx], packed,
                                       __ATOMIC_RELAXED, __HIP_MEMORY_SCOPE_AGENT);
                    if (t == TT - 1) {
                        out[YOFF + BB * HH + (size_t)b * HH + hidx] = h;       // h_n[1]
                        out[YOFF + 3 * BB * HH + (size_t)b * HH + hidx] = c;   // c_n[1]
                    }
                }
            }
        }
        // ---- monotonic two-level grid barrier, RELAXED AGENT atomics only ----
        if (s < TT) {
            __syncthreads();   // drains each thread's vmcnt -> sc1 stores visible
            if (tid == 0) {
                asm volatile("s_waitcnt vmcnt(0)" ::: "memory");
                ++epoch;
                unsigned* leafp = bar + 64 + ((unsigned)bid >> 4) * 32;
                const unsigned r = __hip_atomic_fetch_add(leafp, 1u, __ATOMIC_RELAXED,
                                                          __HIP_MEMORY_SCOPE_AGENT);
                if (r == 16u * epoch - 1u) {
                    __hip_atomic_fetch_add(bar, 1u, __ATOMIC_RELAXED,
                                           __HIP_MEMORY_SCOPE_AGENT);
                }
                const unsigned tgt = 16u * epoch;
                while (__hip_atomic_load(bar, __ATOMIC_RELAXED,
                                         __HIP_MEMORY_SCOPE_AGENT) < tgt) {
                    __builtin_amdgcn_s_sleep(1);
                }
            }
            __syncthreads();
        }
    }
}

extern "C" void kernel_launch(void* const* d_in, const int* in_sizes, int n_in,
                              void* d_out, int out_size, void* d_ws, size_t ws_size,
                              hipStream_t stream) {
    (void)in_sizes; (void)n_in; (void)out_size; (void)ws_size;
    const float* x  = (const float*)d_in[0];
    const float* W0 = (const float*)d_in[1];
    const float* b0 = (const float*)d_in[2];
    const float* W1 = (const float*)d_in[3];
    const float* b1 = (const float*)d_in[4];
    float* out = (float*)d_out;
    unsigned* hws = (unsigned*)d_ws;  // 2 buffers x [2][64][512] u32 = 512 KB
    unsigned* bar = (unsigned*)((char*)d_ws + 2 * 2 * 64 * 512 * sizeof(unsigned));

    hipMemsetAsync(d_ws, 0, 2 * 2 * 64 * 512 * sizeof(unsigned) + 4096, stream);

    void* args[] = { (void*)&x, (void*)&W0, (void*)&b0, (void*)&W1, (void*)&b1,
                     (void*)&out, (void*)&hws, (void*)&bar };
    hipLaunchCooperativeKernel(reinterpret_cast<const void*>(lstm_fused),
                               dim3(256), dim3(512), args, 0u, stream);
}